// Round 6
// baseline (745.694 us; speedup 1.0000x reference)
//
#include <hip/hip_runtime.h>
#include <stdint.h>

#define HW     65160      // H*W = 181*360
#define W_LON  360
#define H_LAT  181
#define T_OUT  181
#define NB     2
#define NC     128
#define NF     128
#define NK     3
#define NSEG   (NK * T_OUT)   // 543 segments, id = k*181 + t
#define XROWS  65280          // padded hw rows for xt (255*256)
// sparse LDS: per row r(=dl) two parity copies of the 720-elem duplicated bf16 row,
// stored as uint words: A[j] = elems(2j,2j+1), B[j] = elems(2j+1,2j+2), j in [0,360)
#define RW     720            // words per row (A 360 + B 360)
#define LDSW   (7 * RW + 16)  // + pad so discarded lanes (tid 180..191) stay in-bounds

typedef __attribute__((ext_vector_type(8))) short bf16x8;
typedef __attribute__((ext_vector_type(4))) float f32x4;

#define AS1(p) ((const __attribute__((address_space(1))) void*)(p))
#define AS3(p) ((__attribute__((address_space(3))) void*)(p))

static __device__ inline ushort f2bf(float v) {
    unsigned u = __float_as_uint(v);
    unsigned r = (u + 0x7FFFu + ((u >> 16) & 1u)) >> 16;
    return (ushort)r;
}
static __device__ inline float bf2f(ushort h) {
    return __uint_as_float(((unsigned)h) << 16);
}

// ---------------- prep kernels ----------------

// weight (F,C,K) fp32 -> wt_h/wt_l [k][f][c] bf16 (c contiguous)
__global__ void k_transpose_w(const float* __restrict__ w,
                              ushort* __restrict__ wt_h, ushort* __restrict__ wt_l) {
    int i = blockIdx.x * 256 + threadIdx.x;
    if (i >= NK * NF * NC) return;
    int k = i / (NF * NC);
    int f = (i / NC) % NF;
    int c = i % NC;
    float v = w[(f * NC + c) * NK + k];
    ushort h = f2bf(v);
    ushort l = f2bf(v - bf2f(h));
    wt_h[i] = h;
    wt_l[i] = l;
}

// segment bounds via binary search: entry order is t-major then k, so
// key(n) = (seg%181)*3 + seg/181 is monotone non-decreasing in n.
__global__ void k_bounds(const int* __restrict__ seg, int* __restrict__ row_start,
                         int* __restrict__ row_end, int nnz) {
    int s = blockIdx.x * 256 + threadIdx.x;
    if (s >= NSEG) return;
    int t = s % T_OUT, k = s / T_OUT;
    int key = t * NK + k;
    int lo = 0, hi = nnz;
    while (lo < hi) {                      // lower_bound
        int mid = (lo + hi) >> 1;
        int sm = seg[mid];
        int km = (sm % T_OUT) * NK + sm / T_OUT;
        if (km < key) lo = mid + 1; else hi = mid;
    }
    row_start[s] = lo;
    int lo2 = lo; hi = nnz;
    while (lo2 < hi) {                     // upper_bound
        int mid = (lo2 + hi) >> 1;
        int sm = seg[mid];
        int km = (sm % T_OUT) * NK + sm / T_OUT;
        if (km <= key) lo2 = mid + 1; else hi = mid;
    }
    row_end[s] = lo2;
}

// pack each entry as (lds WORD offset, val*qw[lat]):
//   ofs = dl*RW + (lon&1)*360 + (lon>>1)   (parity selects copy A or B)
// gather lane q reads word ofs+q = bf16 elems (lon+2q, lon+2q+1) of row dl.
__global__ void k_pack(const int* __restrict__ seg, const int* __restrict__ lat,
                       const int* __restrict__ lon, const float* __restrict__ vals,
                       const float* __restrict__ qw,
                       uint2* __restrict__ packed, int nnz) {
    int n = blockIdx.x * 256 + threadIdx.x;
    if (n >= nnz) return;
    int s = seg[n];
    int k = s / T_OUT;
    int t = s - k * T_OUT;
    int la = lat[n];
    int dl = la - (t - 3);
    dl = max(0, min(6, dl));                  // mathematically always in [0,6]
    int lo = lon[n];
    unsigned ofs = (unsigned)(dl * RW + (lo & 1) * 360 + (lo >> 1));
    float v = vals[n] * qw[la];               // fold quadrature weight into psi
    packed[n] = make_uint2(ofs, __float_as_uint(v));
}

// x [b][c][hw] fp32 -> xt_h/xt_l [b][hw][c] bf16 (c contiguous).
// 64-wide hw tile: reads are 256B-contiguous float4 segments per 16 lanes;
// writes are 4KB-contiguous per wave (64 lanes x 64B span each).
__global__ __launch_bounds__(256) void k_split(const float* __restrict__ x,
                                               ushort* __restrict__ xt_h,
                                               ushort* __restrict__ xt_l) {
    int b = blockIdx.y;
    int hw0 = blockIdx.x * 64;
    __shared__ float t[128][65];
    int tid = threadIdx.x;
    int quad = tid & 15;              // 16 quads = 64 floats per row
    int r0 = tid >> 4;                // 16 rows per iteration
    bool full = (hw0 + 64 <= HW);
#pragma unroll
    for (int rr = 0; rr < 8; ++rr) {
        int c = rr * 16 + r0;
        const float* src = x + ((size_t)b * NC + c) * HW + hw0 + quad * 4;
        float4 v;
        if (full) {
            v = *(const float4*)src;
        } else {
            int base = hw0 + quad * 4;
            v.x = (base + 0 < HW) ? src[0] : 0.f;
            v.y = (base + 1 < HW) ? src[1] : 0.f;
            v.z = (base + 2 < HW) ? src[2] : 0.f;
            v.w = (base + 3 < HW) ? src[3] : 0.f;
        }
        *(float4*)&t[c][quad * 4] = v;
    }
    __syncthreads();
    int hwl = tid >> 2;               // 64 hw per block
    int c0 = (tid & 3) * 32;          // 4 c-chunks of 32
    int hw = hw0 + hwl;
    if (hw < HW) {
        ushort hb[32], lb[32];
#pragma unroll
        for (int cc = 0; cc < 32; ++cc) {
            float v = t[c0 + cc][hwl];
            ushort h = f2bf(v);
            hb[cc] = h;
            lb[cc] = f2bf(v - bf2f(h));
        }
        size_t off = ((size_t)b * XROWS + hw) * NC + c0;
#pragma unroll
        for (int j = 0; j < 4; ++j) {
            *(int4*)(xt_h + off + j * 8) = *(int4*)(hb + j * 8);
            *(int4*)(xt_l + off + j * 8) = *(int4*)(lb + j * 8);
        }
    }
}

// ---------------- stage 1: bf16x3 MFMA GEMM ----------------
// z[b][k][fl][hw] = sum_c W[f,c,k]*x[b,c,hw], stored as BF16 (feeds bf16 gather)
template<int MT>
__global__ __launch_bounds__(256)
void k_gemm2(const ushort* __restrict__ xt_h, const ushort* __restrict__ xt_l,
             const ushort* __restrict__ wt_h, const ushort* __restrict__ wt_l,
             ushort* __restrict__ z, int cf0) {
    constexpr int MTILES = MT / 16;
    int tid = threadIdx.x;
    int bk = blockIdx.y;
    int b = bk / NK, k = bk % NK;
    int hwb = blockIdx.x * 256;

    __shared__ ushort smem[2 * MT * 32 + 2 * 256 * 32];
    ushort* Ah = smem;                  // MT rows x 32 c
    ushort* Al = smem + MT * 32;
    ushort* Bh = smem + 2 * MT * 32;    // 256 rows x 32 c
    ushort* Bl = Bh + 256 * 32;

    int lane = tid & 63;
    int wv = tid >> 6;
    int m = lane & 15, q0 = lane >> 4;
    int eoff = (m * 4 + (q0 ^ ((m >> 1) & 3))) * 8;   // ushort offset of this lane's chunk

    f32x4 acc[MTILES][4];
#pragma unroll
    for (int i = 0; i < MTILES; ++i)
#pragma unroll
        for (int j = 0; j < 4; ++j) acc[i][j] = (f32x4){0.f, 0.f, 0.f, 0.f};

    for (int c0 = 0; c0 < NC; c0 += 32) {
        if (tid < MT * 4) {
            int f = tid >> 2, s = tid & 3;
            int q = s ^ ((f >> 1) & 3);
            size_t gi = ((size_t)(k * NF + cf0 + f)) * NC + c0 + q * 8;
            int i0 = tid & ~63;
            __builtin_amdgcn_global_load_lds(AS1(wt_h + gi), AS3(Ah + i0 * 8), 16, 0, 0);
            __builtin_amdgcn_global_load_lds(AS1(wt_l + gi), AS3(Al + i0 * 8), 16, 0, 0);
        }
#pragma unroll
        for (int it = 0; it < 4; ++it) {
            int i = it * 256 + tid;
            int r = i >> 2, s = i & 3;
            int q = s ^ ((r >> 1) & 3);
            size_t gi = ((size_t)b * XROWS + hwb + r) * NC + c0 + q * 8;
            int i0 = i & ~63;
            __builtin_amdgcn_global_load_lds(AS1(xt_h + gi), AS3(Bh + i0 * 8), 16, 0, 0);
            __builtin_amdgcn_global_load_lds(AS1(xt_l + gi), AS3(Bl + i0 * 8), 16, 0, 0);
        }
        __syncthreads();

        bf16x8 ah[MTILES], al[MTILES], bh[4], bl[4];
#pragma unroll
        for (int mt = 0; mt < MTILES; ++mt) {
            ah[mt] = *(const bf16x8*)(Ah + mt * 512 + eoff);
            al[mt] = *(const bf16x8*)(Al + mt * 512 + eoff);
        }
#pragma unroll
        for (int nt = 0; nt < 4; ++nt) {
            int boff = wv * 2048 + nt * 512 + eoff;
            bh[nt] = *(const bf16x8*)(Bh + boff);
            bl[nt] = *(const bf16x8*)(Bl + boff);
        }
#pragma unroll
        for (int mt = 0; mt < MTILES; ++mt)
#pragma unroll
            for (int nt = 0; nt < 4; ++nt) {
                acc[mt][nt] = __builtin_amdgcn_mfma_f32_16x16x32_bf16(ah[mt], bh[nt], acc[mt][nt], 0, 0, 0);
                acc[mt][nt] = __builtin_amdgcn_mfma_f32_16x16x32_bf16(ah[mt], bl[nt], acc[mt][nt], 0, 0, 0);
                acc[mt][nt] = __builtin_amdgcn_mfma_f32_16x16x32_bf16(al[mt], bh[nt], acc[mt][nt], 0, 0, 0);
            }
        __syncthreads();
    }

#pragma unroll
    for (int mt = 0; mt < MTILES; ++mt)
#pragma unroll
        for (int nt = 0; nt < 4; ++nt) {
            int n = hwb + wv * 64 + nt * 16 + m;
            if (n < HW) {
                f32x4 a = acc[mt][nt];
#pragma unroll
                for (int r = 0; r < 4; ++r) {
                    int fl = mt * 16 + q0 * 4 + r;
                    z[((size_t)(b * NK + k) * MT + fl) * HW + n] = f2bf(a[r]);
                }
            }
        }
}

// ---------------- stage 2: gather/accumulate + bias ----------------
// v6: bf16 parity-pair gather. Lane q owns output lons (2q, 2q+1); each entry is a
// single ds_read_b32 of a packed bf16 pair (2 B/value = half the LDS bytes of R5,
// which measured at ~95% of the LDS byte ceiling). Two parity copies per row let
// odd/even entry shifts share the uniform-base + tid addressing (R0 codegen shape).
// LDS 20224 B -> 8 blocks/CU. Pole-first t order kept (R5 win).
__global__ void __launch_bounds__(192)
k_sparse(const ushort* __restrict__ z, const uint2* __restrict__ packed,
         const int* __restrict__ row_start, const int* __restrict__ row_end,
         const float* __restrict__ bias,
         float* __restrict__ out, int cf0, int CF) {
    int y  = blockIdx.y;
    int t  = (y & 1) ? (T_OUT - 1 - (y >> 1)) : (y >> 1);   // pole-first order
    int ch = blockIdx.x;                 // [0, 2*CF)
    int b  = ch / CF;
    int fl = ch % CF;
    int fg = cf0 + fl;
    int tid = threadIdx.x;               // 192; lanes 180..191 discarded
    __shared__ unsigned lds32[LDSW];     // 20224 B

    int lat0 = t - 3;
    float accE = 0.f, accO = 0.f;

    for (int k = 0; k < NK; ++k) {
        __syncthreads();
        const ushort* zplane = &z[(size_t)((b * NK + k) * CF + fl) * HW];
        // stage 7 rows x 360 A-words + 360 B-words
        for (int q = tid; q < 7 * 360; q += 192) {
            int r = q / 360, j = q - r * 360;
            int la = lat0 + r;
            if (la < 0 || la >= H_LAT) continue;
            const unsigned* g = (const unsigned*)(zplane + la * W_LON); // 180 words
            int jm = (j < 180) ? j : j - 180;
            int jn = (jm + 1 < 180) ? jm + 1 : 0;
            unsigned ga = g[jm];
            unsigned gb = g[jn];
            lds32[r * RW + j]       = ga;                       // A: elems (2j,2j+1)
            lds32[r * RW + 360 + j] = (ga >> 16) | (gb << 16);  // B: elems (2j+1,2j+2)
        }
        __syncthreads();

        int s = k * T_OUT + t;
        int ns = row_start[s], ne = row_end[s];
#pragma unroll 4
        for (int n = ns; n < ne; ++n) {
            uint2 e = packed[n];
            float v = __uint_as_float(e.y);
            unsigned u = lds32[(int)e.x + tid];
            accE = fmaf(v, __uint_as_float(u << 16), accE);
            accO = fmaf(v, __uint_as_float(u & 0xFFFF0000u), accO);
        }
    }

    if (tid < 180) {
        float bs = bias[fg];
        size_t ob = (size_t)((b * NF + fg) * T_OUT + t) * W_LON;
        float2 o = make_float2(accE + bs, accO + bs);
        *(float2*)&out[ob + 2 * tid] = o;
    }
}

// ---------------- launch ----------------
extern "C" void kernel_launch(void* const* d_in, const int* in_sizes, int n_in,
                              void* d_out, int out_size, void* d_ws, size_t ws_size,
                              hipStream_t stream) {
    const float* x    = (const float*)d_in[0];
    const float* qw   = (const float*)d_in[1];
    const float* vals = (const float*)d_in[2];
    const float* w    = (const float*)d_in[3];
    const float* bias = (const float*)d_in[4];
    const int*   seg  = (const int*)d_in[5];
    const int*   lat  = (const int*)d_in[6];
    const int*   lon  = (const int*)d_in[7];
    int nnz = in_sizes[2];
    float* out = (float*)d_out;

    char* wsb = (char*)d_ws;
    ushort* wt_h     = (ushort*)wsb;                        // 98304 B
    ushort* wt_l     = (ushort*)(wsb + 98304);              // 98304 B
    int*    row_start= (int*)(wsb + 196608);                // 2304 B
    int*    row_end  = (int*)(wsb + 198912);                // 2304 B
    uint2*  packed   = (uint2*)(wsb + 201216);              // nnz*8 B
    size_t xoff = (201216 + (size_t)nnz * 8 + 255) & ~(size_t)255;
    size_t xtsz = (size_t)NB * XROWS * NC * 2;              // 33,423,360 B each
    ushort* xt_h = (ushort*)(wsb + xoff);
    ushort* xt_l = (ushort*)(wsb + xoff + xtsz);
    size_t zoff = (xoff + 2 * xtsz + 255) & ~(size_t)255;
    ushort* z = (ushort*)(wsb + zoff);
    size_t zavail = (ws_size > zoff) ? ws_size - zoff : 0;

    int CF = 16;
    if      (zavail >= (size_t)64 * 6 * HW * 2) CF = 64;
    else if (zavail >= (size_t)32 * 6 * HW * 2) CF = 32;

    k_transpose_w<<<(NK * NF * NC + 255) / 256, 256, 0, stream>>>(w, wt_h, wt_l);
    k_pack<<<(nnz + 255) / 256, 256, 0, stream>>>(seg, lat, lon, vals, qw, packed, nnz);
    k_bounds<<<(NSEG + 255) / 256, 256, 0, stream>>>(seg, row_start, row_end, nnz);
    k_split<<<dim3((HW + 63) / 64, NB), 256, 0, stream>>>(x, xt_h, xt_l);

    int hwtiles = (HW + 255) / 256;   // 255
    for (int cf0 = 0; cf0 < NF; cf0 += CF) {
        dim3 gg(hwtiles, NB * NK);
        if (CF == 64)      k_gemm2<64><<<gg, 256, 0, stream>>>(xt_h, xt_l, wt_h, wt_l, z, cf0);
        else if (CF == 32) k_gemm2<32><<<gg, 256, 0, stream>>>(xt_h, xt_l, wt_h, wt_l, z, cf0);
        else               k_gemm2<16><<<gg, 256, 0, stream>>>(xt_h, xt_l, wt_h, wt_l, z, cf0);
        dim3 gs(2 * CF, T_OUT);
        k_sparse<<<gs, 192, 0, stream>>>(z, packed, row_start, row_end, bias, out, cf0, CF);
    }
}

// Round 7
// 554.430 us; speedup vs baseline: 1.3450x; 1.3450x over previous
//
#include <hip/hip_runtime.h>
#include <stdint.h>

#define HW     65160      // H*W = 181*360
#define W_LON  360
#define H_LAT  181
#define T_OUT  181
#define NB     2
#define NC     128
#define NF     128
#define NK     3
#define NSEG   (NK * T_OUT)   // 543 segments, id = k*181 + t
#define XROWS  65280          // padded hw rows for xt (255*256)
// sparse LDS: per row r(=dl) two parity copies of the 720-elem duplicated bf16 row,
// stored as uint words: A[j] = elems(2j,2j+1), B[j] = elems(2j+1,2j+2), j in [0,360)
#define RW     720            // words per row (A 360 + B 360)
#define LDSW   (7 * RW + 16)  // + pad so discarded lanes (tid 180..191) stay in-bounds

typedef __attribute__((ext_vector_type(8))) short bf16x8;
typedef __attribute__((ext_vector_type(4))) float f32x4;

#define AS1(p) ((const __attribute__((address_space(1))) void*)(p))
#define AS3(p) ((__attribute__((address_space(3))) void*)(p))

static __device__ inline ushort f2bf(float v) {
    unsigned u = __float_as_uint(v);
    unsigned r = (u + 0x7FFFu + ((u >> 16) & 1u)) >> 16;
    return (ushort)r;
}
static __device__ inline float bf2f(ushort h) {
    return __uint_as_float(((unsigned)h) << 16);
}

// ---------------- prep kernels ----------------

// weight (F,C,K) fp32 -> wt_h/wt_l [k][f][c] bf16 (c contiguous)
__global__ void k_transpose_w(const float* __restrict__ w,
                              ushort* __restrict__ wt_h, ushort* __restrict__ wt_l) {
    int i = blockIdx.x * 256 + threadIdx.x;
    if (i >= NK * NF * NC) return;
    int k = i / (NF * NC);
    int f = (i / NC) % NF;
    int c = i % NC;
    float v = w[(f * NC + c) * NK + k];
    ushort h = f2bf(v);
    ushort l = f2bf(v - bf2f(h));
    wt_h[i] = h;
    wt_l[i] = l;
}

// segment bounds via binary search: entry order is t-major then k, so
// key(n) = (seg%181)*3 + seg/181 is monotone non-decreasing in n.
__global__ void k_bounds(const int* __restrict__ seg, int* __restrict__ row_start,
                         int* __restrict__ row_end, int nnz) {
    int s = blockIdx.x * 256 + threadIdx.x;
    if (s >= NSEG) return;
    int t = s % T_OUT, k = s / T_OUT;
    int key = t * NK + k;
    int lo = 0, hi = nnz;
    while (lo < hi) {                      // lower_bound
        int mid = (lo + hi) >> 1;
        int sm = seg[mid];
        int km = (sm % T_OUT) * NK + sm / T_OUT;
        if (km < key) lo = mid + 1; else hi = mid;
    }
    row_start[s] = lo;
    int lo2 = lo; hi = nnz;
    while (lo2 < hi) {                     // upper_bound
        int mid = (lo2 + hi) >> 1;
        int sm = seg[mid];
        int km = (sm % T_OUT) * NK + sm / T_OUT;
        if (km <= key) lo2 = mid + 1; else hi = mid;
    }
    row_end[s] = lo2;
}

// pack each entry as (lds WORD offset, val*qw[lat]):
//   ofs = dl*RW + (lon&1)*360 + (lon>>1)   (parity selects copy A or B)
// gather lane q reads word ofs+q = bf16 elems (lon+2q, lon+2q+1) of row dl.
__global__ void k_pack(const int* __restrict__ seg, const int* __restrict__ lat,
                       const int* __restrict__ lon, const float* __restrict__ vals,
                       const float* __restrict__ qw,
                       uint2* __restrict__ packed, int nnz) {
    int n = blockIdx.x * 256 + threadIdx.x;
    if (n >= nnz) return;
    int s = seg[n];
    int k = s / T_OUT;
    int t = s - k * T_OUT;
    int la = lat[n];
    int dl = la - (t - 3);
    dl = max(0, min(6, dl));                  // mathematically always in [0,6]
    int lo = lon[n];
    unsigned ofs = (unsigned)(dl * RW + (lo & 1) * 360 + (lo >> 1));
    float v = vals[n] * qw[la];               // fold quadrature weight into psi
    packed[n] = make_uint2(ofs, __float_as_uint(v));
}

// x [b][c][hw] fp32 -> xt_h/xt_l [b][hw][c] bf16 (c contiguous).
// 64-wide hw tile: reads are 256B-contiguous float4 segments per 16 lanes;
// writes are 4KB-contiguous per wave (64 lanes x 64B span each).
__global__ __launch_bounds__(256) void k_split(const float* __restrict__ x,
                                               ushort* __restrict__ xt_h,
                                               ushort* __restrict__ xt_l) {
    int b = blockIdx.y;
    int hw0 = blockIdx.x * 64;
    __shared__ float t[128][65];
    int tid = threadIdx.x;
    int quad = tid & 15;              // 16 quads = 64 floats per row
    int r0 = tid >> 4;                // 16 rows per iteration
    bool full = (hw0 + 64 <= HW);
#pragma unroll
    for (int rr = 0; rr < 8; ++rr) {
        int c = rr * 16 + r0;
        const float* src = x + ((size_t)b * NC + c) * HW + hw0 + quad * 4;
        float4 v;
        if (full) {
            v = *(const float4*)src;
        } else {
            int base = hw0 + quad * 4;
            v.x = (base + 0 < HW) ? src[0] : 0.f;
            v.y = (base + 1 < HW) ? src[1] : 0.f;
            v.z = (base + 2 < HW) ? src[2] : 0.f;
            v.w = (base + 3 < HW) ? src[3] : 0.f;
        }
        *(float4*)&t[c][quad * 4] = v;
    }
    __syncthreads();
    int hwl = tid >> 2;               // 64 hw per block
    int c0 = (tid & 3) * 32;          // 4 c-chunks of 32
    int hw = hw0 + hwl;
    if (hw < HW) {
        ushort hb[32], lb[32];
#pragma unroll
        for (int cc = 0; cc < 32; ++cc) {
            float v = t[c0 + cc][hwl];
            ushort h = f2bf(v);
            hb[cc] = h;
            lb[cc] = f2bf(v - bf2f(h));
        }
        size_t off = ((size_t)b * XROWS + hw) * NC + c0;
#pragma unroll
        for (int j = 0; j < 4; ++j) {
            *(int4*)(xt_h + off + j * 8) = *(int4*)(hb + j * 8);
            *(int4*)(xt_l + off + j * 8) = *(int4*)(lb + j * 8);
        }
    }
}

// ---------------- stage 1: bf16x3 MFMA GEMM ----------------
// z[b][k][fl][hw] = sum_c W[f,c,k]*x[b,c,hw], stored as BF16 (feeds bf16 gather)
template<int MT>
__global__ __launch_bounds__(256)
void k_gemm2(const ushort* __restrict__ xt_h, const ushort* __restrict__ xt_l,
             const ushort* __restrict__ wt_h, const ushort* __restrict__ wt_l,
             ushort* __restrict__ z, int cf0) {
    constexpr int MTILES = MT / 16;
    int tid = threadIdx.x;
    int bk = blockIdx.y;
    int b = bk / NK, k = bk % NK;
    int hwb = blockIdx.x * 256;

    __shared__ ushort smem[2 * MT * 32 + 2 * 256 * 32];
    ushort* Ah = smem;                  // MT rows x 32 c
    ushort* Al = smem + MT * 32;
    ushort* Bh = smem + 2 * MT * 32;    // 256 rows x 32 c
    ushort* Bl = Bh + 256 * 32;

    int lane = tid & 63;
    int wv = tid >> 6;
    int m = lane & 15, q0 = lane >> 4;
    int eoff = (m * 4 + (q0 ^ ((m >> 1) & 3))) * 8;   // ushort offset of this lane's chunk

    f32x4 acc[MTILES][4];
#pragma unroll
    for (int i = 0; i < MTILES; ++i)
#pragma unroll
        for (int j = 0; j < 4; ++j) acc[i][j] = (f32x4){0.f, 0.f, 0.f, 0.f};

    for (int c0 = 0; c0 < NC; c0 += 32) {
        if (tid < MT * 4) {
            int f = tid >> 2, s = tid & 3;
            int q = s ^ ((f >> 1) & 3);
            size_t gi = ((size_t)(k * NF + cf0 + f)) * NC + c0 + q * 8;
            int i0 = tid & ~63;
            __builtin_amdgcn_global_load_lds(AS1(wt_h + gi), AS3(Ah + i0 * 8), 16, 0, 0);
            __builtin_amdgcn_global_load_lds(AS1(wt_l + gi), AS3(Al + i0 * 8), 16, 0, 0);
        }
#pragma unroll
        for (int it = 0; it < 4; ++it) {
            int i = it * 256 + tid;
            int r = i >> 2, s = i & 3;
            int q = s ^ ((r >> 1) & 3);
            size_t gi = ((size_t)b * XROWS + hwb + r) * NC + c0 + q * 8;
            int i0 = i & ~63;
            __builtin_amdgcn_global_load_lds(AS1(xt_h + gi), AS3(Bh + i0 * 8), 16, 0, 0);
            __builtin_amdgcn_global_load_lds(AS1(xt_l + gi), AS3(Bl + i0 * 8), 16, 0, 0);
        }
        __syncthreads();

        bf16x8 ah[MTILES], al[MTILES], bh[4], bl[4];
#pragma unroll
        for (int mt = 0; mt < MTILES; ++mt) {
            ah[mt] = *(const bf16x8*)(Ah + mt * 512 + eoff);
            al[mt] = *(const bf16x8*)(Al + mt * 512 + eoff);
        }
#pragma unroll
        for (int nt = 0; nt < 4; ++nt) {
            int boff = wv * 2048 + nt * 512 + eoff;
            bh[nt] = *(const bf16x8*)(Bh + boff);
            bl[nt] = *(const bf16x8*)(Bl + boff);
        }
#pragma unroll
        for (int mt = 0; mt < MTILES; ++mt)
#pragma unroll
            for (int nt = 0; nt < 4; ++nt) {
                acc[mt][nt] = __builtin_amdgcn_mfma_f32_16x16x32_bf16(ah[mt], bh[nt], acc[mt][nt], 0, 0, 0);
                acc[mt][nt] = __builtin_amdgcn_mfma_f32_16x16x32_bf16(ah[mt], bl[nt], acc[mt][nt], 0, 0, 0);
                acc[mt][nt] = __builtin_amdgcn_mfma_f32_16x16x32_bf16(al[mt], bh[nt], acc[mt][nt], 0, 0, 0);
            }
        __syncthreads();
    }

#pragma unroll
    for (int mt = 0; mt < MTILES; ++mt)
#pragma unroll
        for (int nt = 0; nt < 4; ++nt) {
            int n = hwb + wv * 64 + nt * 16 + m;
            if (n < HW) {
                f32x4 a = acc[mt][nt];
#pragma unroll
                for (int r = 0; r < 4; ++r) {
                    int fl = mt * 16 + q0 * 4 + r;
                    z[((size_t)(b * NK + k) * MT + fl) * HW + n] = f2bf(a[r]);
                }
            }
        }
}

// ---------------- stage 2: gather/accumulate + bias ----------------
// v7 = v6 gather (1x ds_read_b32 bf16 pair per entry, halved LDS pipe) + vectorized
// staging: uint4 chunks, parity-B copy built in registers via alignbit pattern
// ((a_i>>16)|(a_{i+1}<<16)), dup'd uint4 stores. Staging instruction count returns
// to R5 levels (315 uint4 loads + 1260 b128 stores / kplane) -- R6's regression was
// 2520 word-iterations x 2 scalar dword loads, not the gather.
__global__ void __launch_bounds__(192)
k_sparse(const ushort* __restrict__ z, const uint2* __restrict__ packed,
         const int* __restrict__ row_start, const int* __restrict__ row_end,
         const float* __restrict__ bias,
         float* __restrict__ out, int cf0, int CF) {
    int y  = blockIdx.y;
    int t  = (y & 1) ? (T_OUT - 1 - (y >> 1)) : (y >> 1);   // pole-first order
    int ch = blockIdx.x;                 // [0, 2*CF)
    int b  = ch / CF;
    int fl = ch % CF;
    int fg = cf0 + fl;
    int tid = threadIdx.x;               // 192; lanes 180..191 discarded
    __shared__ unsigned lds32[LDSW];     // 20224 B

    int lat0 = t - 3;
    float accE = 0.f, accO = 0.f;

    for (int k = 0; k < NK; ++k) {
        __syncthreads();
        const ushort* zplane = &z[(size_t)((b * NK + k) * CF + fl) * HW];
        // 7 rows x 45 uint4-chunks (180 words/row in global);
        // A copy = natural words (dup at +180), B copy = halfword-shifted (dup at +540)
        for (int c = tid; c < 7 * 45; c += 192) {
            int r = c / 45, cj = (c - r * 45) * 4;
            int la = lat0 + r;
            if (la < 0 || la >= H_LAT) continue;
            const unsigned* g = (const unsigned*)(zplane + la * W_LON);
            uint4 a = *(const uint4*)(g + cj);
            unsigned nx = g[(cj + 4 < 180) ? cj + 4 : 0];
            uint4 bw;
            bw.x = (a.x >> 16) | (a.y << 16);
            bw.y = (a.y >> 16) | (a.z << 16);
            bw.z = (a.z >> 16) | (a.w << 16);
            bw.w = (a.w >> 16) | (nx << 16);
            unsigned* base = &lds32[r * RW + cj];
            *(uint4*)(base)       = a;
            *(uint4*)(base + 180) = a;
            *(uint4*)(base + 360) = bw;
            *(uint4*)(base + 540) = bw;
        }
        __syncthreads();

        int s = k * T_OUT + t;
        int ns = row_start[s], ne = row_end[s];
#pragma unroll 4
        for (int n = ns; n < ne; ++n) {
            uint2 e = packed[n];
            float v = __uint_as_float(e.y);
            unsigned u = lds32[(int)e.x + tid];
            accE = fmaf(v, __uint_as_float(u << 16), accE);
            accO = fmaf(v, __uint_as_float(u & 0xFFFF0000u), accO);
        }
    }

    if (tid < 180) {
        float bs = bias[fg];
        size_t ob = (size_t)((b * NF + fg) * T_OUT + t) * W_LON;
        float2 o = make_float2(accE + bs, accO + bs);
        *(float2*)&out[ob + 2 * tid] = o;
    }
}

// ---------------- launch ----------------
extern "C" void kernel_launch(void* const* d_in, const int* in_sizes, int n_in,
                              void* d_out, int out_size, void* d_ws, size_t ws_size,
                              hipStream_t stream) {
    const float* x    = (const float*)d_in[0];
    const float* qw   = (const float*)d_in[1];
    const float* vals = (const float*)d_in[2];
    const float* w    = (const float*)d_in[3];
    const float* bias = (const float*)d_in[4];
    const int*   seg  = (const int*)d_in[5];
    const int*   lat  = (const int*)d_in[6];
    const int*   lon  = (const int*)d_in[7];
    int nnz = in_sizes[2];
    float* out = (float*)d_out;

    char* wsb = (char*)d_ws;
    ushort* wt_h     = (ushort*)wsb;                        // 98304 B
    ushort* wt_l     = (ushort*)(wsb + 98304);              // 98304 B
    int*    row_start= (int*)(wsb + 196608);                // 2304 B
    int*    row_end  = (int*)(wsb + 198912);                // 2304 B
    uint2*  packed   = (uint2*)(wsb + 201216);              // nnz*8 B
    size_t xoff = (201216 + (size_t)nnz * 8 + 255) & ~(size_t)255;
    size_t xtsz = (size_t)NB * XROWS * NC * 2;              // 33,423,360 B each
    ushort* xt_h = (ushort*)(wsb + xoff);
    ushort* xt_l = (ushort*)(wsb + xoff + xtsz);
    size_t zoff = (xoff + 2 * xtsz + 255) & ~(size_t)255;
    ushort* z = (ushort*)(wsb + zoff);
    size_t zavail = (ws_size > zoff) ? ws_size - zoff : 0;

    int CF = 16;
    if      (zavail >= (size_t)64 * 6 * HW * 2) CF = 64;
    else if (zavail >= (size_t)32 * 6 * HW * 2) CF = 32;

    k_transpose_w<<<(NK * NF * NC + 255) / 256, 256, 0, stream>>>(w, wt_h, wt_l);
    k_pack<<<(nnz + 255) / 256, 256, 0, stream>>>(seg, lat, lon, vals, qw, packed, nnz);
    k_bounds<<<(NSEG + 255) / 256, 256, 0, stream>>>(seg, row_start, row_end, nnz);
    k_split<<<dim3((HW + 63) / 64, NB), 256, 0, stream>>>(x, xt_h, xt_l);

    int hwtiles = (HW + 255) / 256;   // 255
    for (int cf0 = 0; cf0 < NF; cf0 += CF) {
        dim3 gg(hwtiles, NB * NK);
        if (CF == 64)      k_gemm2<64><<<gg, 256, 0, stream>>>(xt_h, xt_l, wt_h, wt_l, z, cf0);
        else if (CF == 32) k_gemm2<32><<<gg, 256, 0, stream>>>(xt_h, xt_l, wt_h, wt_l, z, cf0);
        else               k_gemm2<16><<<gg, 256, 0, stream>>>(xt_h, xt_l, wt_h, wt_l, z, cf0);
        dim3 gs(2 * CF, T_OUT);
        k_sparse<<<gs, 192, 0, stream>>>(z, packed, row_start, row_end, bias, out, cf0, CF);
    }
}

// Round 8
// 552.311 us; speedup vs baseline: 1.3501x; 1.0038x over previous
//
#include <hip/hip_runtime.h>
#include <stdint.h>

#define HW     65160      // H*W = 181*360
#define W_LON  360
#define H_LAT  181
#define T_OUT  181
#define NB     2
#define NC     128
#define NF     128
#define NK     3
#define NSEG   (NK * T_OUT)   // 543 segments, id = k*181 + t
#define XROWS  65280          // padded hw rows for xt (255*256)
// sparse LDS: per row r(=dl) two parity copies of the 720-elem duplicated bf16 row,
// stored as uint words: A[j] = elems(2j,2j+1), B[j] = elems(2j+1,2j+2), j in [0,360)
#define RW     720            // words per row (A 360 + B 360)
#define LDSW   (7 * RW + 16)  // + pad so discarded lanes (tid 180..191) stay in-bounds

typedef __attribute__((ext_vector_type(8))) short bf16x8;
typedef __attribute__((ext_vector_type(4))) float f32x4;
typedef __attribute__((ext_vector_type(2))) float f32x2;

#define AS1(p) ((const __attribute__((address_space(1))) void*)(p))
#define AS3(p) ((__attribute__((address_space(3))) void*)(p))

static __device__ inline ushort f2bf(float v) {
    unsigned u = __float_as_uint(v);
    unsigned r = (u + 0x7FFFu + ((u >> 16) & 1u)) >> 16;
    return (ushort)r;
}
static __device__ inline float bf2f(ushort h) {
    return __uint_as_float(((unsigned)h) << 16);
}

// ---------------- prep kernels ----------------

// weight (F,C,K) fp32 -> wt_h/wt_l [k][f][c] bf16 (c contiguous)
__global__ void k_transpose_w(const float* __restrict__ w,
                              ushort* __restrict__ wt_h, ushort* __restrict__ wt_l) {
    int i = blockIdx.x * 256 + threadIdx.x;
    if (i >= NK * NF * NC) return;
    int k = i / (NF * NC);
    int f = (i / NC) % NF;
    int c = i % NC;
    float v = w[(f * NC + c) * NK + k];
    ushort h = f2bf(v);
    ushort l = f2bf(v - bf2f(h));
    wt_h[i] = h;
    wt_l[i] = l;
}

// segment bounds via binary search: entry order is t-major then k, so
// key(n) = (seg%181)*3 + seg/181 is monotone non-decreasing in n.
__global__ void k_bounds(const int* __restrict__ seg, int* __restrict__ row_start,
                         int* __restrict__ row_end, int nnz) {
    int s = blockIdx.x * 256 + threadIdx.x;
    if (s >= NSEG) return;
    int t = s % T_OUT, k = s / T_OUT;
    int key = t * NK + k;
    int lo = 0, hi = nnz;
    while (lo < hi) {                      // lower_bound
        int mid = (lo + hi) >> 1;
        int sm = seg[mid];
        int km = (sm % T_OUT) * NK + sm / T_OUT;
        if (km < key) lo = mid + 1; else hi = mid;
    }
    row_start[s] = lo;
    int lo2 = lo; hi = nnz;
    while (lo2 < hi) {                     // upper_bound
        int mid = (lo2 + hi) >> 1;
        int sm = seg[mid];
        int km = (sm % T_OUT) * NK + sm / T_OUT;
        if (km <= key) lo2 = mid + 1; else hi = mid;
    }
    row_end[s] = lo2;
}

// pack each entry as (lds WORD offset, val*qw[lat]):
//   ofs = dl*RW + (lon&1)*360 + (lon>>1)   (parity selects copy A or B)
// gather lane q reads word ofs+q = bf16 elems (lon+2q, lon+2q+1) of row dl.
__global__ void k_pack(const int* __restrict__ seg, const int* __restrict__ lat,
                       const int* __restrict__ lon, const float* __restrict__ vals,
                       const float* __restrict__ qw,
                       uint2* __restrict__ packed, int nnz) {
    int n = blockIdx.x * 256 + threadIdx.x;
    if (n >= nnz) return;
    int s = seg[n];
    int k = s / T_OUT;
    int t = s - k * T_OUT;
    int la = lat[n];
    int dl = la - (t - 3);
    dl = max(0, min(6, dl));                  // mathematically always in [0,6]
    int lo = lon[n];
    unsigned ofs = (unsigned)(dl * RW + (lo & 1) * 360 + (lo >> 1));
    float v = vals[n] * qw[la];               // fold quadrature weight into psi
    packed[n] = make_uint2(ofs, __float_as_uint(v));
}

// x [b][c][hw] fp32 -> xt_h/xt_l [b][hw][c] bf16 (c contiguous).
// 64-wide hw tile: reads are 256B-contiguous float4 segments per 16 lanes;
// writes are 4KB-contiguous per wave (64 lanes x 64B span each).
__global__ __launch_bounds__(256) void k_split(const float* __restrict__ x,
                                               ushort* __restrict__ xt_h,
                                               ushort* __restrict__ xt_l) {
    int b = blockIdx.y;
    int hw0 = blockIdx.x * 64;
    __shared__ float t[128][65];
    int tid = threadIdx.x;
    int quad = tid & 15;              // 16 quads = 64 floats per row
    int r0 = tid >> 4;                // 16 rows per iteration
    bool full = (hw0 + 64 <= HW);
#pragma unroll
    for (int rr = 0; rr < 8; ++rr) {
        int c = rr * 16 + r0;
        const float* src = x + ((size_t)b * NC + c) * HW + hw0 + quad * 4;
        float4 v;
        if (full) {
            v = *(const float4*)src;
        } else {
            int base = hw0 + quad * 4;
            v.x = (base + 0 < HW) ? src[0] : 0.f;
            v.y = (base + 1 < HW) ? src[1] : 0.f;
            v.z = (base + 2 < HW) ? src[2] : 0.f;
            v.w = (base + 3 < HW) ? src[3] : 0.f;
        }
        *(float4*)&t[c][quad * 4] = v;
    }
    __syncthreads();
    int hwl = tid >> 2;               // 64 hw per block
    int c0 = (tid & 3) * 32;          // 4 c-chunks of 32
    int hw = hw0 + hwl;
    if (hw < HW) {
        ushort hb[32], lb[32];
#pragma unroll
        for (int cc = 0; cc < 32; ++cc) {
            float v = t[c0 + cc][hwl];
            ushort h = f2bf(v);
            hb[cc] = h;
            lb[cc] = f2bf(v - bf2f(h));
        }
        size_t off = ((size_t)b * XROWS + hw) * NC + c0;
#pragma unroll
        for (int j = 0; j < 4; ++j) {
            *(int4*)(xt_h + off + j * 8) = *(int4*)(hb + j * 8);
            *(int4*)(xt_l + off + j * 8) = *(int4*)(lb + j * 8);
        }
    }
}

// ---------------- stage 1: bf16x2 MFMA GEMM ----------------
// z[b][k][fl][hw] = sum_c W[f,c,k]*x[b,c,hw], stored as BF16.
// v8: 2-pass split (Wh*Xh + Wh*Xl) -- dropped Wl*Xh term is ~2^-9 relative,
// same order as the bf16 rounding of z at the epilogue. 32 MFMA/step vs 48.
template<int MT>
__global__ __launch_bounds__(256)
void k_gemm2(const ushort* __restrict__ xt_h, const ushort* __restrict__ xt_l,
             const ushort* __restrict__ wt_h,
             ushort* __restrict__ z, int cf0) {
    constexpr int MTILES = MT / 16;
    int tid = threadIdx.x;
    int bk = blockIdx.y;
    int b = bk / NK, k = bk % NK;
    int hwb = blockIdx.x * 256;

    __shared__ ushort smem[MT * 32 + 2 * 256 * 32];
    ushort* Ah = smem;                  // MT rows x 32 c
    ushort* Bh = smem + MT * 32;        // 256 rows x 32 c
    ushort* Bl = Bh + 256 * 32;

    int lane = tid & 63;
    int wv = tid >> 6;
    int m = lane & 15, q0 = lane >> 4;
    int eoff = (m * 4 + (q0 ^ ((m >> 1) & 3))) * 8;   // ushort offset of this lane's chunk

    f32x4 acc[MTILES][4];
#pragma unroll
    for (int i = 0; i < MTILES; ++i)
#pragma unroll
        for (int j = 0; j < 4; ++j) acc[i][j] = (f32x4){0.f, 0.f, 0.f, 0.f};

    for (int c0 = 0; c0 < NC; c0 += 32) {
        if (tid < MT * 4) {
            int f = tid >> 2, s = tid & 3;
            int q = s ^ ((f >> 1) & 3);
            size_t gi = ((size_t)(k * NF + cf0 + f)) * NC + c0 + q * 8;
            int i0 = tid & ~63;
            __builtin_amdgcn_global_load_lds(AS1(wt_h + gi), AS3(Ah + i0 * 8), 16, 0, 0);
        }
#pragma unroll
        for (int it = 0; it < 4; ++it) {
            int i = it * 256 + tid;
            int r = i >> 2, s = i & 3;
            int q = s ^ ((r >> 1) & 3);
            size_t gi = ((size_t)b * XROWS + hwb + r) * NC + c0 + q * 8;
            int i0 = i & ~63;
            __builtin_amdgcn_global_load_lds(AS1(xt_h + gi), AS3(Bh + i0 * 8), 16, 0, 0);
            __builtin_amdgcn_global_load_lds(AS1(xt_l + gi), AS3(Bl + i0 * 8), 16, 0, 0);
        }
        __syncthreads();

        bf16x8 ah[MTILES], bh[4], bl[4];
#pragma unroll
        for (int mt = 0; mt < MTILES; ++mt)
            ah[mt] = *(const bf16x8*)(Ah + mt * 512 + eoff);
#pragma unroll
        for (int nt = 0; nt < 4; ++nt) {
            int boff = wv * 2048 + nt * 512 + eoff;
            bh[nt] = *(const bf16x8*)(Bh + boff);
            bl[nt] = *(const bf16x8*)(Bl + boff);
        }
#pragma unroll
        for (int mt = 0; mt < MTILES; ++mt)
#pragma unroll
            for (int nt = 0; nt < 4; ++nt) {
                acc[mt][nt] = __builtin_amdgcn_mfma_f32_16x16x32_bf16(ah[mt], bh[nt], acc[mt][nt], 0, 0, 0);
                acc[mt][nt] = __builtin_amdgcn_mfma_f32_16x16x32_bf16(ah[mt], bl[nt], acc[mt][nt], 0, 0, 0);
            }
        __syncthreads();
    }

#pragma unroll
    for (int mt = 0; mt < MTILES; ++mt)
#pragma unroll
        for (int nt = 0; nt < 4; ++nt) {
            int n = hwb + wv * 64 + nt * 16 + m;
            if (n < HW) {
                f32x4 a = acc[mt][nt];
#pragma unroll
                for (int r = 0; r < 4; ++r) {
                    int fl = mt * 16 + q0 * 4 + r;
                    z[((size_t)(b * NK + k) * MT + fl) * HW + n] = f2bf(a[r]);
                }
            }
        }
}

// ---------------- stage 2: gather/accumulate + bias ----------------
// v8 = v7 structure + packed f32x2 accumulation (targets v_pk_fma_f32: one packed
// fma per entry instead of two scalar fmas; k_sparse is VALU-issue-bound per R7
// pipe accounting). Loop shape (single-entry, uniform base + tid, unroll 4) kept
// verbatim -- that shape is what produces the pipelined VGPR-40 codegen.
__global__ void __launch_bounds__(192)
k_sparse(const ushort* __restrict__ z, const uint2* __restrict__ packed,
         const int* __restrict__ row_start, const int* __restrict__ row_end,
         const float* __restrict__ bias,
         float* __restrict__ out, int cf0, int CF) {
    int y  = blockIdx.y;
    int t  = (y & 1) ? (T_OUT - 1 - (y >> 1)) : (y >> 1);   // pole-first order
    int ch = blockIdx.x;                 // [0, 2*CF)
    int b  = ch / CF;
    int fl = ch % CF;
    int fg = cf0 + fl;
    int tid = threadIdx.x;               // 192; lanes 180..191 discarded
    __shared__ unsigned lds32[LDSW];     // 20224 B

    int lat0 = t - 3;
    f32x2 acc = {0.f, 0.f};

    for (int k = 0; k < NK; ++k) {
        __syncthreads();
        const ushort* zplane = &z[(size_t)((b * NK + k) * CF + fl) * HW];
        // 7 rows x 45 uint4-chunks (180 words/row in global);
        // A copy = natural words (dup at +180), B copy = halfword-shifted (dup at +540)
        for (int c = tid; c < 7 * 45; c += 192) {
            int r = c / 45, cj = (c - r * 45) * 4;
            int la = lat0 + r;
            if (la < 0 || la >= H_LAT) continue;
            const unsigned* g = (const unsigned*)(zplane + la * W_LON);
            uint4 a = *(const uint4*)(g + cj);
            unsigned nx = g[(cj + 4 < 180) ? cj + 4 : 0];
            uint4 bw;
            bw.x = (a.x >> 16) | (a.y << 16);
            bw.y = (a.y >> 16) | (a.z << 16);
            bw.z = (a.z >> 16) | (a.w << 16);
            bw.w = (a.w >> 16) | (nx << 16);
            unsigned* base = &lds32[r * RW + cj];
            *(uint4*)(base)       = a;
            *(uint4*)(base + 180) = a;
            *(uint4*)(base + 360) = bw;
            *(uint4*)(base + 540) = bw;
        }
        __syncthreads();

        int s = k * T_OUT + t;
        int ns = row_start[s], ne = row_end[s];
#pragma unroll 4
        for (int n = ns; n < ne; ++n) {
            uint2 e = packed[n];
            float v = __uint_as_float(e.y);
            unsigned u = lds32[(int)e.x + tid];
            f32x2 xv;
            xv[0] = __uint_as_float(u << 16);
            xv[1] = __uint_as_float(u & 0xFFFF0000u);
            f32x2 vv = {v, v};
#if __has_builtin(__builtin_elementwise_fma)
            acc = __builtin_elementwise_fma(vv, xv, acc);
#else
            acc[0] = fmaf(v, xv[0], acc[0]);
            acc[1] = fmaf(v, xv[1], acc[1]);
#endif
        }
    }

    if (tid < 180) {
        float bs = bias[fg];
        size_t ob = (size_t)((b * NF + fg) * T_OUT + t) * W_LON;
        float2 o = make_float2(acc[0] + bs, acc[1] + bs);
        *(float2*)&out[ob + 2 * tid] = o;
    }
}

// ---------------- launch ----------------
extern "C" void kernel_launch(void* const* d_in, const int* in_sizes, int n_in,
                              void* d_out, int out_size, void* d_ws, size_t ws_size,
                              hipStream_t stream) {
    const float* x    = (const float*)d_in[0];
    const float* qw   = (const float*)d_in[1];
    const float* vals = (const float*)d_in[2];
    const float* w    = (const float*)d_in[3];
    const float* bias = (const float*)d_in[4];
    const int*   seg  = (const int*)d_in[5];
    const int*   lat  = (const int*)d_in[6];
    const int*   lon  = (const int*)d_in[7];
    int nnz = in_sizes[2];
    float* out = (float*)d_out;

    char* wsb = (char*)d_ws;
    ushort* wt_h     = (ushort*)wsb;                        // 98304 B
    ushort* wt_l     = (ushort*)(wsb + 98304);              // 98304 B (unused by gemm v8)
    int*    row_start= (int*)(wsb + 196608);                // 2304 B
    int*    row_end  = (int*)(wsb + 198912);                // 2304 B
    uint2*  packed   = (uint2*)(wsb + 201216);              // nnz*8 B
    size_t xoff = (201216 + (size_t)nnz * 8 + 255) & ~(size_t)255;
    size_t xtsz = (size_t)NB * XROWS * NC * 2;              // 33,423,360 B each
    ushort* xt_h = (ushort*)(wsb + xoff);
    ushort* xt_l = (ushort*)(wsb + xoff + xtsz);
    size_t zoff = (xoff + 2 * xtsz + 255) & ~(size_t)255;
    ushort* z = (ushort*)(wsb + zoff);
    size_t zavail = (ws_size > zoff) ? ws_size - zoff : 0;

    int CF = 16;
    if      (zavail >= (size_t)64 * 6 * HW * 2) CF = 64;
    else if (zavail >= (size_t)32 * 6 * HW * 2) CF = 32;

    k_transpose_w<<<(NK * NF * NC + 255) / 256, 256, 0, stream>>>(w, wt_h, wt_l);
    k_pack<<<(nnz + 255) / 256, 256, 0, stream>>>(seg, lat, lon, vals, qw, packed, nnz);
    k_bounds<<<(NSEG + 255) / 256, 256, 0, stream>>>(seg, row_start, row_end, nnz);
    k_split<<<dim3((HW + 63) / 64, NB), 256, 0, stream>>>(x, xt_h, xt_l);

    int hwtiles = (HW + 255) / 256;   // 255
    for (int cf0 = 0; cf0 < NF; cf0 += CF) {
        dim3 gg(hwtiles, NB * NK);
        if (CF == 64)      k_gemm2<64><<<gg, 256, 0, stream>>>(xt_h, xt_l, wt_h, z, cf0);
        else if (CF == 32) k_gemm2<32><<<gg, 256, 0, stream>>>(xt_h, xt_l, wt_h, z, cf0);
        else               k_gemm2<16><<<gg, 256, 0, stream>>>(xt_h, xt_l, wt_h, z, cf0);
        dim3 gs(2 * CF, T_OUT);
        k_sparse<<<gs, 192, 0, stream>>>(z, packed, row_start, row_end, bias, out, cf0, CF);
    }
}

// Round 9
// 471.060 us; speedup vs baseline: 1.5830x; 1.1725x over previous
//
#include <hip/hip_runtime.h>
#include <stdint.h>

#define HW     65160      // H*W = 181*360
#define W_LON  360
#define H_LAT  181
#define T_OUT  181
#define NB     2
#define NC     128
#define NF     128
#define NK     3
#define NSEG   (NK * T_OUT)   // 543 segments, id = k*181 + t
#define XROWS  65280          // padded hw rows for xt (255*256)
// sparse LDS: per row r(=dl) two parity copies of the 720-elem duplicated bf16 row,
// stored as uint words: A[j] = elems(2j,2j+1), B[j] = elems(2j+1,2j+2), j in [0,360)
#define RW     720            // words per row (A 360 + B 360)
#define LDSW   (7 * RW + 16)  // + pad so discarded lanes (tid 180..191) stay in-bounds

typedef __attribute__((ext_vector_type(8))) short bf16x8;
typedef __attribute__((ext_vector_type(4))) float f32x4;
typedef __attribute__((ext_vector_type(2))) float f32x2;

#define AS1(p) ((const __attribute__((address_space(1))) void*)(p))
#define AS3(p) ((__attribute__((address_space(3))) void*)(p))

static __device__ inline ushort f2bf(float v) {
    unsigned u = __float_as_uint(v);
    unsigned r = (u + 0x7FFFu + ((u >> 16) & 1u)) >> 16;
    return (ushort)r;
}
static __device__ inline float bf2f(ushort h) {
    return __uint_as_float(((unsigned)h) << 16);
}

// ---------------- prep kernels ----------------

// weight (F,C,K) fp32 -> wt_h/wt_l [k][f][c] bf16 (c contiguous)
__global__ void k_transpose_w(const float* __restrict__ w,
                              ushort* __restrict__ wt_h, ushort* __restrict__ wt_l) {
    int i = blockIdx.x * 256 + threadIdx.x;
    if (i >= NK * NF * NC) return;
    int k = i / (NF * NC);
    int f = (i / NC) % NF;
    int c = i % NC;
    float v = w[(f * NC + c) * NK + k];
    ushort h = f2bf(v);
    ushort l = f2bf(v - bf2f(h));
    wt_h[i] = h;
    wt_l[i] = l;
}

// segment bounds via binary search: entry order is t-major then k, so
// key(n) = (seg%181)*3 + seg/181 is monotone non-decreasing in n.
__global__ void k_bounds(const int* __restrict__ seg, int* __restrict__ row_start,
                         int* __restrict__ row_end, int nnz) {
    int s = blockIdx.x * 256 + threadIdx.x;
    if (s >= NSEG) return;
    int t = s % T_OUT, k = s / T_OUT;
    int key = t * NK + k;
    int lo = 0, hi = nnz;
    while (lo < hi) {                      // lower_bound
        int mid = (lo + hi) >> 1;
        int sm = seg[mid];
        int km = (sm % T_OUT) * NK + sm / T_OUT;
        if (km < key) lo = mid + 1; else hi = mid;
    }
    row_start[s] = lo;
    int lo2 = lo; hi = nnz;
    while (lo2 < hi) {                     // upper_bound
        int mid = (lo2 + hi) >> 1;
        int sm = seg[mid];
        int km = (sm % T_OUT) * NK + sm / T_OUT;
        if (km <= key) lo2 = mid + 1; else hi = mid;
    }
    row_end[s] = lo2;
}

// pack each entry as (lds WORD offset, val*qw[lat]):
//   ofs = dl*RW + (lon&1)*360 + (lon>>1)   (parity selects copy A or B)
// gather lane q reads word ofs+q = bf16 elems (lon+2q, lon+2q+1) of row dl.
__global__ void k_pack(const int* __restrict__ seg, const int* __restrict__ lat,
                       const int* __restrict__ lon, const float* __restrict__ vals,
                       const float* __restrict__ qw,
                       uint2* __restrict__ packed, int nnz) {
    int n = blockIdx.x * 256 + threadIdx.x;
    if (n >= nnz) return;
    int s = seg[n];
    int k = s / T_OUT;
    int t = s - k * T_OUT;
    int la = lat[n];
    int dl = la - (t - 3);
    dl = max(0, min(6, dl));                  // mathematically always in [0,6]
    int lo = lon[n];
    unsigned ofs = (unsigned)(dl * RW + (lo & 1) * 360 + (lo >> 1));
    float v = vals[n] * qw[la];               // fold quadrature weight into psi
    packed[n] = make_uint2(ofs, __float_as_uint(v));
}

// x [b][c][hw] fp32 -> xt_h [b][hw][c] bf16 (c contiguous). v9: hi-part only
// (GEMM passes are (Wh+Wl)*Xh; dropped Wh*Xl is first-order 2^-9, same order as
// R8's dropped Wl*Xh which left absmax unchanged).
__global__ __launch_bounds__(256) void k_split(const float* __restrict__ x,
                                               ushort* __restrict__ xt_h) {
    int b = blockIdx.y;
    int hw0 = blockIdx.x * 64;
    __shared__ float t[128][65];
    int tid = threadIdx.x;
    int quad = tid & 15;              // 16 quads = 64 floats per row
    int r0 = tid >> 4;                // 16 rows per iteration
    bool full = (hw0 + 64 <= HW);
#pragma unroll
    for (int rr = 0; rr < 8; ++rr) {
        int c = rr * 16 + r0;
        const float* src = x + ((size_t)b * NC + c) * HW + hw0 + quad * 4;
        float4 v;
        if (full) {
            v = *(const float4*)src;
        } else {
            int base = hw0 + quad * 4;
            v.x = (base + 0 < HW) ? src[0] : 0.f;
            v.y = (base + 1 < HW) ? src[1] : 0.f;
            v.z = (base + 2 < HW) ? src[2] : 0.f;
            v.w = (base + 3 < HW) ? src[3] : 0.f;
        }
        *(float4*)&t[c][quad * 4] = v;
    }
    __syncthreads();
    int hwl = tid >> 2;               // 64 hw per block
    int c0 = (tid & 3) * 32;          // 4 c-chunks of 32
    int hw = hw0 + hwl;
    if (hw < HW) {
        ushort hb[32];
#pragma unroll
        for (int cc = 0; cc < 32; ++cc)
            hb[cc] = f2bf(t[c0 + cc][hwl]);
        size_t off = ((size_t)b * XROWS + hw) * NC + c0;
#pragma unroll
        for (int j = 0; j < 4; ++j)
            *(int4*)(xt_h + off + j * 8) = *(int4*)(hb + j * 8);
    }
}

// ---------------- stage 1: bf16 MFMA GEMM ----------------
// z[b][k][zbase+fl][hw] = sum_c (Wh+Wl)[f,c,k]*Xh[b,c,hw], stored BF16.
// v9: B = Bh only (staging loads 12->6 per c-step, LDS 36.9->24.6KB -> 6 blocks/CU).
template<int MT>
__global__ __launch_bounds__(256)
void k_gemm2(const ushort* __restrict__ xt_h,
             const ushort* __restrict__ wt_h, const ushort* __restrict__ wt_l,
             ushort* __restrict__ z, int cf0, int zcf, int zbase) {
    constexpr int MTILES = MT / 16;
    int tid = threadIdx.x;
    int bk = blockIdx.y;
    int b = bk / NK, k = bk % NK;
    int hwb = blockIdx.x * 256;

    __shared__ ushort smem[2 * MT * 32 + 256 * 32];
    ushort* Ah = smem;                  // MT rows x 32 c
    ushort* Al = smem + MT * 32;
    ushort* Bh = smem + 2 * MT * 32;    // 256 rows x 32 c

    int lane = tid & 63;
    int wv = tid >> 6;
    int m = lane & 15, q0 = lane >> 4;
    int eoff = (m * 4 + (q0 ^ ((m >> 1) & 3))) * 8;   // ushort offset of this lane's chunk

    f32x4 acc[MTILES][4];
#pragma unroll
    for (int i = 0; i < MTILES; ++i)
#pragma unroll
        for (int j = 0; j < 4; ++j) acc[i][j] = (f32x4){0.f, 0.f, 0.f, 0.f};

    for (int c0 = 0; c0 < NC; c0 += 32) {
        if (tid < MT * 4) {
            int f = tid >> 2, s = tid & 3;
            int q = s ^ ((f >> 1) & 3);
            size_t gi = ((size_t)(k * NF + cf0 + f)) * NC + c0 + q * 8;
            int i0 = tid & ~63;
            __builtin_amdgcn_global_load_lds(AS1(wt_h + gi), AS3(Ah + i0 * 8), 16, 0, 0);
            __builtin_amdgcn_global_load_lds(AS1(wt_l + gi), AS3(Al + i0 * 8), 16, 0, 0);
        }
#pragma unroll
        for (int it = 0; it < 4; ++it) {
            int i = it * 256 + tid;
            int r = i >> 2, s = i & 3;
            int q = s ^ ((r >> 1) & 3);
            size_t gi = ((size_t)b * XROWS + hwb + r) * NC + c0 + q * 8;
            int i0 = i & ~63;
            __builtin_amdgcn_global_load_lds(AS1(xt_h + gi), AS3(Bh + i0 * 8), 16, 0, 0);
        }
        __syncthreads();

        bf16x8 ah[MTILES], al[MTILES], bh[4];
#pragma unroll
        for (int mt = 0; mt < MTILES; ++mt) {
            ah[mt] = *(const bf16x8*)(Ah + mt * 512 + eoff);
            al[mt] = *(const bf16x8*)(Al + mt * 512 + eoff);
        }
#pragma unroll
        for (int nt = 0; nt < 4; ++nt)
            bh[nt] = *(const bf16x8*)(Bh + wv * 2048 + nt * 512 + eoff);
#pragma unroll
        for (int mt = 0; mt < MTILES; ++mt)
#pragma unroll
            for (int nt = 0; nt < 4; ++nt) {
                acc[mt][nt] = __builtin_amdgcn_mfma_f32_16x16x32_bf16(ah[mt], bh[nt], acc[mt][nt], 0, 0, 0);
                acc[mt][nt] = __builtin_amdgcn_mfma_f32_16x16x32_bf16(al[mt], bh[nt], acc[mt][nt], 0, 0, 0);
            }
        __syncthreads();
    }

#pragma unroll
    for (int mt = 0; mt < MTILES; ++mt)
#pragma unroll
        for (int nt = 0; nt < 4; ++nt) {
            int n = hwb + wv * 64 + nt * 16 + m;
            if (n < HW) {
                f32x4 a = acc[mt][nt];
#pragma unroll
                for (int r = 0; r < 4; ++r) {
                    int fl = mt * 16 + q0 * 4 + r;
                    z[((size_t)(b * NK + k) * zcf + zbase + fl) * HW + n] = f2bf(a[r]);
                }
            }
        }
}

// ---------------- stage 2: gather/accumulate + bias ----------------
// v9 = v7/v8 gather (unchanged) + T14 async staging: next k-plane's uint4 loads are
// issued into registers BEFORE the current plane's gather (HBM/L2 latency hides under
// ~1000s of gather cycles); LDS write happens after the barrier. Gather loop kept
// byte-identical to R8 (codegen fragility lesson R1/R4).
__global__ void __launch_bounds__(192)
k_sparse(const ushort* __restrict__ z, const uint2* __restrict__ packed,
         const int* __restrict__ row_start, const int* __restrict__ row_end,
         const float* __restrict__ bias,
         float* __restrict__ out, int cf0, int CF) {
    int y  = blockIdx.y;
    int t  = (y & 1) ? (T_OUT - 1 - (y >> 1)) : (y >> 1);   // pole-first order
    int ch = blockIdx.x;                 // [0, 2*CF)
    int b  = ch / CF;
    int fl = ch % CF;
    int fg = cf0 + fl;
    int tid = threadIdx.x;               // 192; lanes 180..191 discarded
    __shared__ unsigned lds32[LDSW];     // 20224 B

    int lat0 = t - 3;
    f32x2 acc = {0.f, 0.f};

    // fixed per-thread staging slots (7 rows x 45 uint4-chunks = 315)
    int c0s = tid,        r0s = c0s / 45, cj0 = (c0s - r0s * 45) * 4, la0 = lat0 + r0s;
    int c1s = tid + 192;
    int r1s = c1s / 45,   cj1 = (c1s - r1s * 45) * 4, la1 = lat0 + r1s;
    bool v0 = (la0 >= 0 && la0 < H_LAT);
    bool v1 = (c1s < 315) && (la1 >= 0 && la1 < H_LAT);
    const size_t zpstride = (size_t)CF * HW;
    const ushort* zb = &z[(size_t)(b * NK) * zpstride + (size_t)fl * HW];

    uint4 a0, a1; unsigned n0 = 0, n1 = 0;
    a0 = (uint4){0,0,0,0}; a1 = (uint4){0,0,0,0};

    // prologue: load k=0
    {
        const unsigned* g0 = (const unsigned*)(zb + la0 * W_LON);
        const unsigned* g1 = (const unsigned*)(zb + la1 * W_LON);
        if (v0) { a0 = *(const uint4*)(g0 + cj0); n0 = g0[(cj0 + 4 < 180) ? cj0 + 4 : 0]; }
        if (v1) { a1 = *(const uint4*)(g1 + cj1); n1 = g1[(cj1 + 4 < 180) ? cj1 + 4 : 0]; }
    }

    for (int k = 0; k < NK; ++k) {
        __syncthreads();                 // previous gather done reading LDS
        // write staged regs for plane k
        if (v0) {
            uint4 bw;
            bw.x = (a0.x >> 16) | (a0.y << 16);
            bw.y = (a0.y >> 16) | (a0.z << 16);
            bw.z = (a0.z >> 16) | (a0.w << 16);
            bw.w = (a0.w >> 16) | (n0 << 16);
            unsigned* base = &lds32[r0s * RW + cj0];
            *(uint4*)(base)       = a0;
            *(uint4*)(base + 180) = a0;
            *(uint4*)(base + 360) = bw;
            *(uint4*)(base + 540) = bw;
        }
        if (v1) {
            uint4 bw;
            bw.x = (a1.x >> 16) | (a1.y << 16);
            bw.y = (a1.y >> 16) | (a1.z << 16);
            bw.z = (a1.z >> 16) | (a1.w << 16);
            bw.w = (a1.w >> 16) | (n1 << 16);
            unsigned* base = &lds32[r1s * RW + cj1];
            *(uint4*)(base)       = a1;
            *(uint4*)(base + 180) = a1;
            *(uint4*)(base + 360) = bw;
            *(uint4*)(base + 540) = bw;
        }
        __syncthreads();

        // issue next plane's loads; latency hides under the gather below
        if (k + 1 < NK) {
            const ushort* zp = zb + (size_t)(k + 1) * zpstride;
            const unsigned* g0 = (const unsigned*)(zp + la0 * W_LON);
            const unsigned* g1 = (const unsigned*)(zp + la1 * W_LON);
            if (v0) { a0 = *(const uint4*)(g0 + cj0); n0 = g0[(cj0 + 4 < 180) ? cj0 + 4 : 0]; }
            if (v1) { a1 = *(const uint4*)(g1 + cj1); n1 = g1[(cj1 + 4 < 180) ? cj1 + 4 : 0]; }
        }

        int s = k * T_OUT + t;
        int ns = row_start[s], ne = row_end[s];
#pragma unroll 4
        for (int n = ns; n < ne; ++n) {
            uint2 e = packed[n];
            float v = __uint_as_float(e.y);
            unsigned u = lds32[(int)e.x + tid];
            f32x2 xv;
            xv[0] = __uint_as_float(u << 16);
            xv[1] = __uint_as_float(u & 0xFFFF0000u);
            f32x2 vv = {v, v};
#if __has_builtin(__builtin_elementwise_fma)
            acc = __builtin_elementwise_fma(vv, xv, acc);
#else
            acc[0] = fmaf(v, xv[0], acc[0]);
            acc[1] = fmaf(v, xv[1], acc[1]);
#endif
        }
    }

    if (tid < 180) {
        float bs = bias[fg];
        size_t ob = (size_t)((b * NF + fg) * T_OUT + t) * W_LON;
        float2 o = make_float2(acc[0] + bs, acc[1] + bs);
        *(float2*)&out[ob + 2 * tid] = o;
    }
}

// ---------------- launch ----------------
extern "C" void kernel_launch(void* const* d_in, const int* in_sizes, int n_in,
                              void* d_out, int out_size, void* d_ws, size_t ws_size,
                              hipStream_t stream) {
    const float* x    = (const float*)d_in[0];
    const float* qw   = (const float*)d_in[1];
    const float* vals = (const float*)d_in[2];
    const float* w    = (const float*)d_in[3];
    const float* bias = (const float*)d_in[4];
    const int*   seg  = (const int*)d_in[5];
    const int*   lat  = (const int*)d_in[6];
    const int*   lon  = (const int*)d_in[7];
    int nnz = in_sizes[2];
    float* out = (float*)d_out;

    char* wsb = (char*)d_ws;
    ushort* wt_h     = (ushort*)wsb;                        // 98304 B
    ushort* wt_l     = (ushort*)(wsb + 98304);              // 98304 B
    int*    row_start= (int*)(wsb + 196608);                // 2304 B
    int*    row_end  = (int*)(wsb + 198912);                // 2304 B
    uint2*  packed   = (uint2*)(wsb + 201216);              // nnz*8 B
    size_t xoff = (201216 + (size_t)nnz * 8 + 255) & ~(size_t)255;
    size_t xtsz = (size_t)NB * XROWS * NC * 2;              // 33,423,360 B (xt_h only)
    ushort* xt_h = (ushort*)(wsb + xoff);
    size_t zoff = (xoff + xtsz + 255) & ~(size_t)255;
    ushort* z = (ushort*)(wsb + zoff);
    size_t zavail = (ws_size > zoff) ? ws_size - zoff : 0;

    int CF = 16;
    if      (zavail >= (size_t)128 * 6 * HW * 2) CF = 128;
    else if (zavail >= (size_t)64 * 6 * HW * 2)  CF = 64;
    else if (zavail >= (size_t)32 * 6 * HW * 2)  CF = 32;

    k_transpose_w<<<(NK * NF * NC + 255) / 256, 256, 0, stream>>>(w, wt_h, wt_l);
    k_pack<<<(nnz + 255) / 256, 256, 0, stream>>>(seg, lat, lon, vals, qw, packed, nnz);
    k_bounds<<<(NSEG + 255) / 256, 256, 0, stream>>>(seg, row_start, row_end, nnz);
    k_split<<<dim3((HW + 63) / 64, NB), 256, 0, stream>>>(x, xt_h);

    int hwtiles = (HW + 255) / 256;   // 255
    int mt = (CF < 64) ? CF : 64;
    for (int zf0 = 0; zf0 < NF; zf0 += CF) {
        for (int cf0 = zf0; cf0 < zf0 + CF; cf0 += mt) {
            dim3 gg(hwtiles, NB * NK);
            if (mt == 64)      k_gemm2<64><<<gg, 256, 0, stream>>>(xt_h, wt_h, wt_l, z, cf0, CF, cf0 - zf0);
            else if (mt == 32) k_gemm2<32><<<gg, 256, 0, stream>>>(xt_h, wt_h, wt_l, z, cf0, CF, cf0 - zf0);
            else               k_gemm2<16><<<gg, 256, 0, stream>>>(xt_h, wt_h, wt_l, z, cf0, CF, cf0 - zf0);
        }
        dim3 gs(2 * CF, T_OUT);
        k_sparse<<<gs, 192, 0, stream>>>(z, packed, row_start, row_end, bias, out, zf0, CF);
    }
}